// Round 4
// baseline (682.930 us; speedup 1.0000x reference)
//
#include <hip/hip_runtime.h>
#include <hip/hip_fp16.h>
#include <math.h>

#define F_IN 128
#define D_OUT 64
#define LRELU 0.2f
#define BN_EPS 1e-3f

typedef __attribute__((ext_vector_type(8))) __bf16 bf16x8;
typedef __attribute__((ext_vector_type(4))) float f32x4;

// ---------------- BN statistics: per-column sum / sumsq ----------------
__global__ __launch_bounds__(256) void stats_kernel(const float* __restrict__ x,
                                                    float* __restrict__ sum,
                                                    float* __restrict__ sumsq,
                                                    int N, int rowsPerBlock) {
    int col  = threadIdx.x & 127;
    int half = threadIdx.x >> 7;
    int rbeg = blockIdx.x * rowsPerBlock;
    int rend = min(rbeg + rowsPerBlock, N);
    float s = 0.f, sq = 0.f;
    for (int r = rbeg + half; r < rend; r += 2) {
        float v = x[(size_t)r * F_IN + col];
        s += v; sq += v * v;
    }
    __shared__ float ls[256], lsq[256];
    ls[threadIdx.x] = s; lsq[threadIdx.x] = sq;
    __syncthreads();
    if (half == 0) {
        s  += ls[col + 128];
        sq += lsq[col + 128];
        atomicAdd(&sum[col], s);
        atomicAdd(&sumsq[col], sq);
    }
}

__global__ void finalize_stats(float* sum, float* sumsq, int N) {
    int c = threadIdx.x;  // 128 threads
    float mean = sum[c] / (float)N;
    float var  = sumsq[c] / (float)N - mean * mean;
    sum[c]   = mean;
    sumsq[c] = rsqrtf(var + BN_EPS);
}

// ---------------- prep: Bt[c][k] = [K1|K2|W][k][c] split into bf16 hi/lo ----------------
__global__ __launch_bounds__(256) void prep_B(const float* __restrict__ K1,
                                              const float* __restrict__ K2,
                                              const float* __restrict__ W,
                                              __bf16* __restrict__ Bth,
                                              __bf16* __restrict__ Btl) {
    int i = blockIdx.x * 256 + threadIdx.x;   // i = c*128 + k, c in [0,320)
    if (i >= 320 * 128) return;
    int c = i >> 7, k = i & 127;
    float v;
    if (c < 128)      v = K1[k * 128 + c];
    else if (c < 256) v = K2[k * 128 + (c - 128)];
    else              v = W[k * 64 + (c - 256)];
    __bf16 h = (__bf16)v;
    Bth[i] = h;
    Btl[i] = (__bf16)(v - (float)h);
}

// ---------------- per-node MFMA, no LDS staging, short acc chains ----------------
__global__ __launch_bounds__(256, 4) void node_kernel(const float* __restrict__ x,
                                                      const __bf16* __restrict__ Bth,
                                                      const __bf16* __restrict__ Btl,
                                                      const float* __restrict__ meanv,
                                                      const float* __restrict__ rstdv,
                                                      float* __restrict__ a1,
                                                      float* __restrict__ a2,
                                                      __half* __restrict__ mapped,
                                                      int N) {
    __shared__ float mS[128], rS[128];
    int tid = threadIdx.x;
    if (tid < 128) { mS[tid] = meanv[tid]; rS[tid] = rstdv[tid]; }
    __syncthreads();

    int lane  = tid & 63;
    int w     = tid >> 6;        // wave = 16-node m-tile
    int col16 = lane & 15;
    int quad  = lane >> 4;
    int kb    = quad * 8;
    int base  = blockIdx.x * 64;
    int arow  = base + w * 16 + col16;
    bool rowok = arow < N;
    const float* xrow = x + (size_t)(rowok ? arow : 0) * F_IN;

    // A fragments straight from global (x-tile is L1-resident), normalize+split in regs
    bf16x8 Ah[4], Al[4];
#pragma unroll
    for (int ks = 0; ks < 4; ++ks) {
        int c0 = ks * 32 + kb;
        float4 v0 = make_float4(0.f, 0.f, 0.f, 0.f), v1 = v0;
        if (rowok) {
            v0 = *(const float4*)&xrow[c0];
            v1 = *(const float4*)&xrow[c0 + 4];
        }
        float4 m0 = *(const float4*)&mS[c0], m1 = *(const float4*)&mS[c0 + 4];
        float4 r0 = *(const float4*)&rS[c0], r1 = *(const float4*)&rS[c0 + 4];
        float f[8] = {(v0.x - m0.x) * r0.x, (v0.y - m0.y) * r0.y,
                      (v0.z - m0.z) * r0.z, (v0.w - m0.w) * r0.w,
                      (v1.x - m1.x) * r1.x, (v1.y - m1.y) * r1.y,
                      (v1.z - m1.z) * r1.z, (v1.w - m1.w) * r1.w};
        bf16x8 hv, lv;
#pragma unroll
        for (int j = 0; j < 8; ++j) {
            __bf16 h = (__bf16)f[j];
            hv[j] = h;
            lv[j] = (__bf16)(f[j] - (float)h);
        }
        Ah[ks] = hv; Al[ks] = lv;
    }

    float pa1[4] = {0, 0, 0, 0}, pa2[4] = {0, 0, 0, 0};

    // paired K1/K2 col-tiles; 6 independent depth-4 MFMA chains
    for (int ct = 0; ct < 8; ++ct) {
        const __bf16* p1h = Bth + (size_t)(ct * 16 + col16) * 128 + kb;
        const __bf16* p1l = Btl + (size_t)(ct * 16 + col16) * 128 + kb;
        f32x4 c1h = {0, 0, 0, 0}, c1m = {0, 0, 0, 0}, c1l = {0, 0, 0, 0};
        f32x4 c2h = {0, 0, 0, 0}, c2m = {0, 0, 0, 0}, c2l = {0, 0, 0, 0};
#pragma unroll
        for (int ks = 0; ks < 4; ++ks) {
            bf16x8 B1h = *(const bf16x8*)(p1h + ks * 32);
            bf16x8 B1l = *(const bf16x8*)(p1l + ks * 32);
            bf16x8 B2h = *(const bf16x8*)(p1h + 128 * 128 + ks * 32);
            bf16x8 B2l = *(const bf16x8*)(p1l + 128 * 128 + ks * 32);
            c1h = __builtin_amdgcn_mfma_f32_16x16x32_bf16(Ah[ks], B1h, c1h, 0, 0, 0);
            c1m = __builtin_amdgcn_mfma_f32_16x16x32_bf16(Al[ks], B1h, c1m, 0, 0, 0);
            c1l = __builtin_amdgcn_mfma_f32_16x16x32_bf16(Ah[ks], B1l, c1l, 0, 0, 0);
            c2h = __builtin_amdgcn_mfma_f32_16x16x32_bf16(Ah[ks], B2h, c2h, 0, 0, 0);
            c2m = __builtin_amdgcn_mfma_f32_16x16x32_bf16(Al[ks], B2h, c2m, 0, 0, 0);
            c2l = __builtin_amdgcn_mfma_f32_16x16x32_bf16(Ah[ks], B2l, c2l, 0, 0, 0);
        }
        // epilogue: dot with xn column slice (L1-hit reload, exact fp32)
        int cg = ct * 16 + col16;
        float mc = mS[cg], rc = rS[cg];
#pragma unroll
        for (int reg = 0; reg < 4; ++reg) {
            int lr = base + w * 16 + quad * 4 + reg;
            float xv = (lr < N) ? (x[(size_t)lr * F_IN + cg] - mc) * rc : 0.f;
            pa1[reg] += (c1h[reg] + c1m[reg] + c1l[reg]) * xv;
            pa2[reg] += (c2h[reg] + c2m[reg] + c2l[reg]) * xv;
        }
    }

    // mapped = xn @ W (cols 256..319), stored fp16
    for (int ct = 0; ct < 4; ++ct) {
        const __bf16* pwh = Bth + (size_t)(256 + ct * 16 + col16) * 128 + kb;
        const __bf16* pwl = Btl + (size_t)(256 + ct * 16 + col16) * 128 + kb;
        f32x4 ch = {0, 0, 0, 0}, cm = {0, 0, 0, 0}, cl = {0, 0, 0, 0};
#pragma unroll
        for (int ks = 0; ks < 4; ++ks) {
            bf16x8 Bh = *(const bf16x8*)(pwh + ks * 32);
            bf16x8 Bl = *(const bf16x8*)(pwl + ks * 32);
            ch = __builtin_amdgcn_mfma_f32_16x16x32_bf16(Ah[ks], Bh, ch, 0, 0, 0);
            cm = __builtin_amdgcn_mfma_f32_16x16x32_bf16(Al[ks], Bh, cm, 0, 0, 0);
            cl = __builtin_amdgcn_mfma_f32_16x16x32_bf16(Ah[ks], Bl, cl, 0, 0, 0);
        }
#pragma unroll
        for (int reg = 0; reg < 4; ++reg) {
            int node = base + w * 16 + quad * 4 + reg;
            if (node < N)
                mapped[(size_t)node * 64 + ct * 16 + col16] =
                    __float2half(ch[reg] + cm[reg] + cl[reg]);
        }
    }

    // reduce a1/a2 partials across the 16 col lanes of each quad
#pragma unroll
    for (int off = 1; off < 16; off <<= 1) {
#pragma unroll
        for (int reg = 0; reg < 4; ++reg) {
            pa1[reg] += __shfl_xor(pa1[reg], off, 64);
            pa2[reg] += __shfl_xor(pa2[reg], off, 64);
        }
    }
    if (col16 == 0) {
#pragma unroll
        for (int reg = 0; reg < 4; ++reg) {
            int node = base + w * 16 + quad * 4 + reg;
            if (node < N) {
                a1[node] = tanhf(pa1[reg]);
                a2[node] = tanhf(pa2[reg]);
            }
        }
    }
}

// ---------------- degree histogram ----------------
__global__ __launch_bounds__(256) void deg_kernel(const int* __restrict__ src,
                                                  int* __restrict__ deg, int E) {
    int e = blockIdx.x * 256 + threadIdx.x;
    if (e < E) atomicAdd(&deg[src[e]], 1);
}

// ---------------- exclusive scan of deg -> rowptr ----------------
__global__ __launch_bounds__(256) void scan1(const int* __restrict__ deg,
                                             int* __restrict__ pos,
                                             int* __restrict__ bsums, int N) {
    __shared__ int s[256];
    int i = blockIdx.x * 256 + threadIdx.x;
    int v = (i < N) ? deg[i] : 0;
    s[threadIdx.x] = v;
    for (int off = 1; off < 256; off <<= 1) {
        __syncthreads();
        int t = (threadIdx.x >= off) ? s[threadIdx.x - off] : 0;
        __syncthreads();
        s[threadIdx.x] += t;
    }
    __syncthreads();
    if (i < N) pos[i] = s[threadIdx.x];
    if (threadIdx.x == 255) bsums[blockIdx.x] = s[255];
}

__global__ __launch_bounds__(512) void scan2(int* bsums, int nb) {
    __shared__ int s[512];
    int v = (threadIdx.x < nb) ? bsums[threadIdx.x] : 0;
    s[threadIdx.x] = v;
    for (int off = 1; off < 512; off <<= 1) {
        __syncthreads();
        int t = (threadIdx.x >= off) ? s[threadIdx.x - off] : 0;
        __syncthreads();
        s[threadIdx.x] += t;
    }
    __syncthreads();
    if (threadIdx.x < nb) bsums[threadIdx.x] = s[threadIdx.x] - v;
}

__global__ __launch_bounds__(256) void scan3(const int* __restrict__ deg,
                                             int* __restrict__ pos,
                                             const int* __restrict__ bsums,
                                             int* __restrict__ rowptr, int N, int E) {
    int i = blockIdx.x * 256 + threadIdx.x;
    if (i < N) {
        int excl = pos[i] - deg[i] + bsums[blockIdx.x];
        rowptr[i] = excl;
        pos[i] = excl;
    }
    if (i == 0) rowptr[N] = E;
}

// ---------------- fused: edge score + counting-sort scatter ----------------
__global__ __launch_bounds__(256) void scatter_kernel(const int* __restrict__ src,
                                                      const int* __restrict__ dst,
                                                      const float* __restrict__ adj,
                                                      const float* __restrict__ a1,
                                                      const float* __restrict__ a2,
                                                      int* __restrict__ pos,
                                                      int2* __restrict__ sorted,
                                                      int E) {
    int e = blockIdx.x * 256 + threadIdx.x;
    if (e >= E) return;
    int s = src[e], d = dst[e];
    float v = adj[e] * (a1[s] + a2[d]);
    v = (v > 0.f) ? v : LRELU * v;
    float ex = __expf(v);   // max-shift skipped: identical math, e bounded
    int p = atomicAdd(&pos[s], 1);
    sorted[p] = make_int2(d, __float_as_int(ex));
}

// ---------------- SpMM (fp16 gather) + inline softmax denom + tanh ----------------
__global__ __launch_bounds__(256) void spmm_kernel(const int* __restrict__ rowptr,
                                                   const int2* __restrict__ sorted,
                                                   const __half2* __restrict__ mapped,
                                                   float* __restrict__ out, int N) {
    int w    = threadIdx.x >> 6;
    int lane = threadIdx.x & 63;
    int node = blockIdx.x * 4 + w;
    if (node >= N) return;
    int ep = lane >> 5;       // edge parity
    int c2 = lane & 31;       // half2 column pair
    int beg = rowptr[node], end = rowptr[node + 1];
    float ax = 0.f, ay = 0.f, accw = 0.f;
    for (int e = beg + ep; e < end; e += 2) {
        int2 pe  = sorted[e];
        float wg = __int_as_float(pe.y);
        float2 m = __half22float2(mapped[(size_t)pe.x * 32 + c2]);
        accw += wg;
        ax += wg * m.x;
        ay += wg * m.y;
    }
    ax   += __shfl_xor(ax, 32, 64);
    ay   += __shfl_xor(ay, 32, 64);
    accw += __shfl_xor(accw, 32, 64);
    if (lane < 32) {
        float inv = (accw != 0.f) ? 1.f / accw : 0.f;
        float2 o = make_float2(tanhf(ax * inv), tanhf(ay * inv));
        *(float2*)&out[(size_t)node * 64 + c2 * 2] = o;
    }
}

extern "C" void kernel_launch(void* const* d_in, const int* in_sizes, int n_in,
                              void* d_out, int out_size, void* d_ws, size_t ws_size,
                              hipStream_t stream) {
    const float* x   = (const float*)d_in[0];
    const int*   src = (const int*)d_in[1];
    const int*   dst = (const int*)d_in[2];
    const float* adj = (const float*)d_in[3];
    const float* W   = (const float*)d_in[4];
    const float* K1  = (const float*)d_in[5];
    const float* K2  = (const float*)d_in[6];
    float* out = (float*)d_out;

    const int N = in_sizes[0] / F_IN;
    const int E = in_sizes[1];

    // workspace layout
    float* meanv  = (float*)d_ws;                 // 128
    float* rstdv  = meanv + 128;                  // 128
    int*   deg    = (int*)(rstdv + 128);          // N (contiguous with stats: one memset)
    float* a1     = (float*)(deg + N);            // N
    float* a2     = a1 + N;                       // N
    __half* mapped = (__half*)(a2 + N);           // N*64 fp16
    int*   rowptr = (int*)(mapped + (size_t)N * 64); // N+1
    int*   pos    = rowptr + (N + 1);             // N
    int*   bsums  = pos + N;                      // 1024
    uintptr_t sp  = ((uintptr_t)(bsums + 1024) + 15) & ~(uintptr_t)15;
    int2*  sorted = (int2*)sp;                    // E
    __bf16* Bth   = (__bf16*)(sorted + E);        // 320*128
    __bf16* Btl   = Bth + 320 * 128;              // 320*128

    // zero stats sums + deg
    hipMemsetAsync(d_ws, 0, (size_t)(256 + N) * sizeof(float), stream);

    deg_kernel<<<(E + 255) / 256, 256, 0, stream>>>(src, deg, E);

    int rpb = (N + 511) / 512;
    stats_kernel<<<512, 256, 0, stream>>>(x, meanv, rstdv, N, rpb);
    finalize_stats<<<1, 128, 0, stream>>>(meanv, rstdv, N);

    prep_B<<<(320 * 128 + 255) / 256, 256, 0, stream>>>(K1, K2, W, Bth, Btl);

    node_kernel<<<(N + 63) / 64, 256, 0, stream>>>(x, Bth, Btl, meanv, rstdv,
                                                   a1, a2, mapped, N);

    int nb1 = (N + 255) / 256;
    scan1<<<nb1, 256, 0, stream>>>(deg, pos, bsums, N);
    scan2<<<1, 512, 0, stream>>>(bsums, nb1);
    scan3<<<nb1, 256, 0, stream>>>(deg, pos, bsums, rowptr, N, E);

    scatter_kernel<<<(E + 255) / 256, 256, 0, stream>>>(src, dst, adj, a1, a2,
                                                        pos, sorted, E);

    spmm_kernel<<<(N + 3) / 4, 256, 0, stream>>>(rowptr, sorted,
                                                 (const __half2*)mapped, out, N);
}

// Round 5
// 561.668 us; speedup vs baseline: 1.2159x; 1.2159x over previous
//
#include <hip/hip_runtime.h>
#include <hip/hip_fp16.h>
#include <math.h>

#define F_IN 128
#define D_OUT 64
#define LRELU 0.2f
#define BN_EPS 1e-3f

typedef __attribute__((ext_vector_type(8))) __bf16 bf16x8;
typedef __attribute__((ext_vector_type(4))) float f32x4;

// ---------------- BN statistics: per-column sum / sumsq ----------------
__global__ __launch_bounds__(256) void stats_kernel(const float* __restrict__ x,
                                                    float* __restrict__ sum,
                                                    float* __restrict__ sumsq,
                                                    int N, int rowsPerBlock) {
    int col  = threadIdx.x & 127;
    int half = threadIdx.x >> 7;
    int rbeg = blockIdx.x * rowsPerBlock;
    int rend = min(rbeg + rowsPerBlock, N);
    float s = 0.f, sq = 0.f;
    for (int r = rbeg + half; r < rend; r += 2) {
        float v = x[(size_t)r * F_IN + col];
        s += v; sq += v * v;
    }
    __shared__ float ls[256], lsq[256];
    ls[threadIdx.x] = s; lsq[threadIdx.x] = sq;
    __syncthreads();
    if (half == 0) {
        s  += ls[col + 128];
        sq += lsq[col + 128];
        atomicAdd(&sum[col], s);
        atomicAdd(&sumsq[col], sq);
    }
}

__global__ void finalize_stats(float* sum, float* sumsq, int N) {
    int c = threadIdx.x;  // 128 threads
    float mean = sum[c] / (float)N;
    float var  = sumsq[c] / (float)N - mean * mean;
    sum[c]   = mean;
    sumsq[c] = rsqrtf(var + BN_EPS);
}

// ---------------- prep: Bt[c][k] = [K1|K2|W][k][c] split into bf16 hi/lo ----------------
__global__ __launch_bounds__(256) void prep_B(const float* __restrict__ K1,
                                              const float* __restrict__ K2,
                                              const float* __restrict__ W,
                                              __bf16* __restrict__ Bth,
                                              __bf16* __restrict__ Btl) {
    int i = blockIdx.x * 256 + threadIdx.x;   // i = c*128 + k, c in [0,320)
    if (i >= 320 * 128) return;
    int c = i >> 7, k = i & 127;
    float v;
    if (c < 128)      v = K1[k * 128 + c];
    else if (c < 256) v = K2[k * 128 + (c - 128)];
    else              v = W[k * 64 + (c - 256)];
    __bf16 h = (__bf16)v;
    Bth[i] = h;
    Btl[i] = (__bf16)(v - (float)h);
}

// ---------------- per-node MFMA, no LDS staging, short acc chains ----------------
// launch_bounds(256,2): 256-VGPR cap. (256,4) capped at 64 VGPR -> scratch
// spills -> 399 MB of scratch writes, 2x slower (round-4 post-mortem).
__global__ __launch_bounds__(256, 2) void node_kernel(const float* __restrict__ x,
                                                      const __bf16* __restrict__ Bth,
                                                      const __bf16* __restrict__ Btl,
                                                      const float* __restrict__ meanv,
                                                      const float* __restrict__ rstdv,
                                                      float* __restrict__ a1,
                                                      float* __restrict__ a2,
                                                      __half* __restrict__ mapped,
                                                      int N) {
    __shared__ float mS[128], rS[128];
    int tid = threadIdx.x;
    if (tid < 128) { mS[tid] = meanv[tid]; rS[tid] = rstdv[tid]; }
    __syncthreads();

    int lane  = tid & 63;
    int w     = tid >> 6;        // wave = 16-node m-tile
    int col16 = lane & 15;
    int quad  = lane >> 4;
    int kb    = quad * 8;
    int base  = blockIdx.x * 64;
    int arow  = base + w * 16 + col16;
    bool rowok = arow < N;
    const float* xrow = x + (size_t)(rowok ? arow : 0) * F_IN;

    // A fragments straight from global (x-tile is L1-resident), normalize+split in regs
    bf16x8 Ah[4], Al[4];
#pragma unroll
    for (int ks = 0; ks < 4; ++ks) {
        int c0 = ks * 32 + kb;
        float4 v0 = make_float4(0.f, 0.f, 0.f, 0.f), v1 = v0;
        if (rowok) {
            v0 = *(const float4*)&xrow[c0];
            v1 = *(const float4*)&xrow[c0 + 4];
        }
        float4 m0 = *(const float4*)&mS[c0], m1 = *(const float4*)&mS[c0 + 4];
        float4 r0 = *(const float4*)&rS[c0], r1 = *(const float4*)&rS[c0 + 4];
        float f[8] = {(v0.x - m0.x) * r0.x, (v0.y - m0.y) * r0.y,
                      (v0.z - m0.z) * r0.z, (v0.w - m0.w) * r0.w,
                      (v1.x - m1.x) * r1.x, (v1.y - m1.y) * r1.y,
                      (v1.z - m1.z) * r1.z, (v1.w - m1.w) * r1.w};
        bf16x8 hv, lv;
#pragma unroll
        for (int j = 0; j < 8; ++j) {
            __bf16 h = (__bf16)f[j];
            hv[j] = h;
            lv[j] = (__bf16)(f[j] - (float)h);
        }
        Ah[ks] = hv; Al[ks] = lv;
    }

    float pa1[4] = {0, 0, 0, 0}, pa2[4] = {0, 0, 0, 0};

    // paired K1/K2 col-tiles; 6 independent depth-4 MFMA chains
    for (int ct = 0; ct < 8; ++ct) {
        const __bf16* p1h = Bth + (size_t)(ct * 16 + col16) * 128 + kb;
        const __bf16* p1l = Btl + (size_t)(ct * 16 + col16) * 128 + kb;
        f32x4 c1h = {0, 0, 0, 0}, c1m = {0, 0, 0, 0}, c1l = {0, 0, 0, 0};
        f32x4 c2h = {0, 0, 0, 0}, c2m = {0, 0, 0, 0}, c2l = {0, 0, 0, 0};
#pragma unroll
        for (int ks = 0; ks < 4; ++ks) {
            bf16x8 B1h = *(const bf16x8*)(p1h + ks * 32);
            bf16x8 B1l = *(const bf16x8*)(p1l + ks * 32);
            bf16x8 B2h = *(const bf16x8*)(p1h + 128 * 128 + ks * 32);
            bf16x8 B2l = *(const bf16x8*)(p1l + 128 * 128 + ks * 32);
            c1h = __builtin_amdgcn_mfma_f32_16x16x32_bf16(Ah[ks], B1h, c1h, 0, 0, 0);
            c1m = __builtin_amdgcn_mfma_f32_16x16x32_bf16(Al[ks], B1h, c1m, 0, 0, 0);
            c1l = __builtin_amdgcn_mfma_f32_16x16x32_bf16(Ah[ks], B1l, c1l, 0, 0, 0);
            c2h = __builtin_amdgcn_mfma_f32_16x16x32_bf16(Ah[ks], B2h, c2h, 0, 0, 0);
            c2m = __builtin_amdgcn_mfma_f32_16x16x32_bf16(Al[ks], B2h, c2m, 0, 0, 0);
            c2l = __builtin_amdgcn_mfma_f32_16x16x32_bf16(Ah[ks], B2l, c2l, 0, 0, 0);
        }
        // epilogue: dot with xn column slice (L1-hit reload, exact fp32)
        int cg = ct * 16 + col16;
        float mc = mS[cg], rc = rS[cg];
#pragma unroll
        for (int reg = 0; reg < 4; ++reg) {
            int lr = base + w * 16 + quad * 4 + reg;
            float xv = (lr < N) ? (x[(size_t)lr * F_IN + cg] - mc) * rc : 0.f;
            pa1[reg] += (c1h[reg] + c1m[reg] + c1l[reg]) * xv;
            pa2[reg] += (c2h[reg] + c2m[reg] + c2l[reg]) * xv;
        }
    }

    // mapped = xn @ W (cols 256..319), stored fp16
    for (int ct = 0; ct < 4; ++ct) {
        const __bf16* pwh = Bth + (size_t)(256 + ct * 16 + col16) * 128 + kb;
        const __bf16* pwl = Btl + (size_t)(256 + ct * 16 + col16) * 128 + kb;
        f32x4 ch = {0, 0, 0, 0}, cm = {0, 0, 0, 0}, cl = {0, 0, 0, 0};
#pragma unroll
        for (int ks = 0; ks < 4; ++ks) {
            bf16x8 Bh = *(const bf16x8*)(pwh + ks * 32);
            bf16x8 Bl = *(const bf16x8*)(pwl + ks * 32);
            ch = __builtin_amdgcn_mfma_f32_16x16x32_bf16(Ah[ks], Bh, ch, 0, 0, 0);
            cm = __builtin_amdgcn_mfma_f32_16x16x32_bf16(Al[ks], Bh, cm, 0, 0, 0);
            cl = __builtin_amdgcn_mfma_f32_16x16x32_bf16(Ah[ks], Bl, cl, 0, 0, 0);
        }
#pragma unroll
        for (int reg = 0; reg < 4; ++reg) {
            int node = base + w * 16 + quad * 4 + reg;
            if (node < N)
                mapped[(size_t)node * 64 + ct * 16 + col16] =
                    __float2half(ch[reg] + cm[reg] + cl[reg]);
        }
    }

    // reduce a1/a2 partials across the 16 col lanes of each quad
#pragma unroll
    for (int off = 1; off < 16; off <<= 1) {
#pragma unroll
        for (int reg = 0; reg < 4; ++reg) {
            pa1[reg] += __shfl_xor(pa1[reg], off, 64);
            pa2[reg] += __shfl_xor(pa2[reg], off, 64);
        }
    }
    if (col16 == 0) {
#pragma unroll
        for (int reg = 0; reg < 4; ++reg) {
            int node = base + w * 16 + quad * 4 + reg;
            if (node < N) {
                a1[node] = tanhf(pa1[reg]);
                a2[node] = tanhf(pa2[reg]);
            }
        }
    }
}

// ---------------- degree histogram ----------------
__global__ __launch_bounds__(256) void deg_kernel(const int* __restrict__ src,
                                                  int* __restrict__ deg, int E) {
    int e = blockIdx.x * 256 + threadIdx.x;
    if (e < E) atomicAdd(&deg[src[e]], 1);
}

// ---------------- exclusive scan of deg -> rowptr ----------------
__global__ __launch_bounds__(256) void scan1(const int* __restrict__ deg,
                                             int* __restrict__ pos,
                                             int* __restrict__ bsums, int N) {
    __shared__ int s[256];
    int i = blockIdx.x * 256 + threadIdx.x;
    int v = (i < N) ? deg[i] : 0;
    s[threadIdx.x] = v;
    for (int off = 1; off < 256; off <<= 1) {
        __syncthreads();
        int t = (threadIdx.x >= off) ? s[threadIdx.x - off] : 0;
        __syncthreads();
        s[threadIdx.x] += t;
    }
    __syncthreads();
    if (i < N) pos[i] = s[threadIdx.x];
    if (threadIdx.x == 255) bsums[blockIdx.x] = s[255];
}

__global__ __launch_bounds__(512) void scan2(int* bsums, int nb) {
    __shared__ int s[512];
    int v = (threadIdx.x < nb) ? bsums[threadIdx.x] : 0;
    s[threadIdx.x] = v;
    for (int off = 1; off < 512; off <<= 1) {
        __syncthreads();
        int t = (threadIdx.x >= off) ? s[threadIdx.x - off] : 0;
        __syncthreads();
        s[threadIdx.x] += t;
    }
    __syncthreads();
    if (threadIdx.x < nb) bsums[threadIdx.x] = s[threadIdx.x] - v;
}

__global__ __launch_bounds__(256) void scan3(const int* __restrict__ deg,
                                             int* __restrict__ pos,
                                             const int* __restrict__ bsums,
                                             int* __restrict__ rowptr, int N, int E) {
    int i = blockIdx.x * 256 + threadIdx.x;
    if (i < N) {
        int excl = pos[i] - deg[i] + bsums[blockIdx.x];
        rowptr[i] = excl;
        pos[i] = excl;
    }
    if (i == 0) rowptr[N] = E;
}

// ---------------- fused: edge score + counting-sort scatter ----------------
__global__ __launch_bounds__(256) void scatter_kernel(const int* __restrict__ src,
                                                      const int* __restrict__ dst,
                                                      const float* __restrict__ adj,
                                                      const float* __restrict__ a1,
                                                      const float* __restrict__ a2,
                                                      int* __restrict__ pos,
                                                      int2* __restrict__ sorted,
                                                      int E) {
    int e = blockIdx.x * 256 + threadIdx.x;
    if (e >= E) return;
    int s = src[e], d = dst[e];
    float v = adj[e] * (a1[s] + a2[d]);
    v = (v > 0.f) ? v : LRELU * v;
    float ex = __expf(v);   // max-shift skipped: identical math, e bounded
    int p = atomicAdd(&pos[s], 1);
    sorted[p] = make_int2(d, __float_as_int(ex));
}

// ---------------- SpMM (fp16 gather) + inline softmax denom + tanh ----------------
__global__ __launch_bounds__(256) void spmm_kernel(const int* __restrict__ rowptr,
                                                   const int2* __restrict__ sorted,
                                                   const __half2* __restrict__ mapped,
                                                   float* __restrict__ out, int N) {
    int w    = threadIdx.x >> 6;
    int lane = threadIdx.x & 63;
    int node = blockIdx.x * 4 + w;
    if (node >= N) return;
    int ep = lane >> 5;       // edge parity
    int c2 = lane & 31;       // half2 column pair
    int beg = rowptr[node], end = rowptr[node + 1];
    float ax = 0.f, ay = 0.f, accw = 0.f;
    for (int e = beg + ep; e < end; e += 2) {
        int2 pe  = sorted[e];
        float wg = __int_as_float(pe.y);
        float2 m = __half22float2(mapped[(size_t)pe.x * 32 + c2]);
        accw += wg;
        ax += wg * m.x;
        ay += wg * m.y;
    }
    ax   += __shfl_xor(ax, 32, 64);
    ay   += __shfl_xor(ay, 32, 64);
    accw += __shfl_xor(accw, 32, 64);
    if (lane < 32) {
        float inv = (accw != 0.f) ? 1.f / accw : 0.f;
        float2 o = make_float2(tanhf(ax * inv), tanhf(ay * inv));
        *(float2*)&out[(size_t)node * 64 + c2 * 2] = o;
    }
}

extern "C" void kernel_launch(void* const* d_in, const int* in_sizes, int n_in,
                              void* d_out, int out_size, void* d_ws, size_t ws_size,
                              hipStream_t stream) {
    const float* x   = (const float*)d_in[0];
    const int*   src = (const int*)d_in[1];
    const int*   dst = (const int*)d_in[2];
    const float* adj = (const float*)d_in[3];
    const float* W   = (const float*)d_in[4];
    const float* K1  = (const float*)d_in[5];
    const float* K2  = (const float*)d_in[6];
    float* out = (float*)d_out;

    const int N = in_sizes[0] / F_IN;
    const int E = in_sizes[1];

    // workspace layout
    float* meanv  = (float*)d_ws;                 // 128
    float* rstdv  = meanv + 128;                  // 128
    int*   deg    = (int*)(rstdv + 128);          // N (contiguous with stats: one memset)
    float* a1     = (float*)(deg + N);            // N
    float* a2     = a1 + N;                       // N
    __half* mapped = (__half*)(a2 + N);           // N*64 fp16
    int*   rowptr = (int*)(mapped + (size_t)N * 64); // N+1
    int*   pos    = rowptr + (N + 1);             // N
    int*   bsums  = pos + N;                      // 1024
    uintptr_t sp  = ((uintptr_t)(bsums + 1024) + 15) & ~(uintptr_t)15;
    int2*  sorted = (int2*)sp;                    // E
    __bf16* Bth   = (__bf16*)(sorted + E);        // 320*128
    __bf16* Btl   = Bth + 320 * 128;              // 320*128

    // zero stats sums + deg
    hipMemsetAsync(d_ws, 0, (size_t)(256 + N) * sizeof(float), stream);

    deg_kernel<<<(E + 255) / 256, 256, 0, stream>>>(src, deg, E);

    int rpb = (N + 511) / 512;
    stats_kernel<<<512, 256, 0, stream>>>(x, meanv, rstdv, N, rpb);
    finalize_stats<<<1, 128, 0, stream>>>(meanv, rstdv, N);

    prep_B<<<(320 * 128 + 255) / 256, 256, 0, stream>>>(K1, K2, W, Bth, Btl);

    node_kernel<<<(N + 63) / 64, 256, 0, stream>>>(x, Bth, Btl, meanv, rstdv,
                                                   a1, a2, mapped, N);

    int nb1 = (N + 255) / 256;
    scan1<<<nb1, 256, 0, stream>>>(deg, pos, bsums, N);
    scan2<<<1, 512, 0, stream>>>(bsums, nb1);
    scan3<<<nb1, 256, 0, stream>>>(deg, pos, bsums, rowptr, N, E);

    scatter_kernel<<<(E + 255) / 256, 256, 0, stream>>>(src, dst, adj, a1, a2,
                                                        pos, sorted, E);

    spmm_kernel<<<(N + 3) / 4, 256, 0, stream>>>(rowptr, sorted,
                                                 (const __half2*)mapped, out, N);
}